// Round 1
// baseline (966.423 us; speedup 1.0000x reference)
//
#include <hip/hip_runtime.h>
#include <hip/hip_cooperative_groups.h>
#include <math.h>

namespace cg = cooperative_groups;

#define H  1024
#define H2 2048
#define V  50257
#define L  512
#define NB 1024
#define NT 256
#define NG ((V + 7) / 8)   // 6283 row-groups of 8 logits

__device__ __forceinline__ float dot4(float4 a, float4 b) {
    return a.x*b.x + a.y*b.y + a.z*b.z + a.w*b.w;
}
__device__ __forceinline__ float wave_red_sum(float v) {
    #pragma unroll
    for (int off = 32; off > 0; off >>= 1) v += __shfl_down(v, off, 64);
    return v;
}
__device__ __forceinline__ float wave_red_max(float v) {
    #pragma unroll
    for (int off = 32; off > 0; off >>= 1) v = fmaxf(v, __shfl_down(v, off, 64));
    return v;
}

// One cooperative kernel, 6 phases, 5 grid syncs.
// 1024 blocks x 256 threads = 4 blocks/CU (launch_bounds caps VGPR<=128, LDS 8.2KB)
__global__ void __launch_bounds__(NT, 4) k_fused(
        const int* __restrict__ tok,   const float* __restrict__ h0,
        const float* __restrict__ enc, const float* __restrict__ emb_w,
        const float* __restrict__ Wc,  const float* __restrict__ bc,
        const float* __restrict__ w_ih,const float* __restrict__ w_hh,
        const float* __restrict__ b_ih,const float* __restrict__ b_hh,
        const float* __restrict__ out_w,const float* __restrict__ out_b,
        float* __restrict__ d_out,     float* __restrict__ ws)
{
    cg::grid_group grid = cg::this_grid();
    __shared__ float4 sh4[512];     // 8 KiB: comb (P3) / hnew (P5)
    __shared__ float  sred[8];

    float* scores = ws;             // 512
    float* gh     = ws + 1024;      // 3072
    float* attn   = ws + 4096;      // 1024
    float* xv     = ws + 5120;      // 1024
    float* hnew   = ws + 6144;      // 1024
    float* pm     = ws + 7168;      // 1024
    float* ps     = ws + 8192;      // 1024

    const int t = threadIdx.x, lane = t & 63, wv = t >> 6;
    const int b = blockIdx.x;

    // ---------- P1: attention scores (512 items) + gh GEMV (768 items) ----------
    for (int it = b; it < 512 + 768; it += NB) {
        if (it < 512) {
            const float4* er = (const float4*)(enc + (size_t)it * H);
            float acc = wave_red_sum(dot4(er[t], ((const float4*)h0)[t]));
            if (lane == 0) sred[wv] = acc;
            __syncthreads();
            if (t == 0) scores[it] = sred[0] + sred[1] + sred[2] + sred[3];
            __syncthreads();
        } else {
            int row = (it - 512) * 4 + wv;              // 0..3071
            const float4* wr = (const float4*)(w_hh + (size_t)row * H);
            const float4* h4 = (const float4*)h0;
            float acc = 0.f;
            #pragma unroll
            for (int j = 0; j < 4; ++j) acc += dot4(wr[j*64 + lane], h4[j*64 + lane]);
            acc = wave_red_sum(acc);
            if (lane == 0) gh[row] = acc + b_hh[row];
        }
    }
    grid.sync();

    // ---------- P2: softmax over 512 scores (redundant/block) + attn col b ----------
    {
        float s0 = scores[t], s1 = scores[t + 256];
        float m = wave_red_max(fmaxf(s0, s1));
        if (lane == 0) sred[wv] = m;
        __syncthreads();
        float gmax = fmaxf(fmaxf(sred[0], sred[1]), fmaxf(sred[2], sred[3]));
        __syncthreads();
        float e0 = expf(s0 - gmax), e1 = expf(s1 - gmax);
        float ssum = wave_red_sum(e0 + e1);
        if (lane == 0) sred[wv] = ssum;
        __syncthreads();
        float inv = 1.f / (sred[0] + sred[1] + sred[2] + sred[3]);
        __syncthreads();
        float w0 = e0 * inv, w1 = e1 * inv;
        if (b == 0) {                                   // attn_weights output
            d_out[V + H + t]       = w0;
            d_out[V + H + 256 + t] = w1;
        }
        // attn_applied[b] = sum_l w[l] * enc[l, b]   (enc col b, L2/L3-hot)
        float acc = w0 * enc[(size_t)t * H + b] + w1 * enc[(size_t)(t + 256) * H + b];
        acc = wave_red_sum(acc);
        if (lane == 0) sred[wv] = acc;
        __syncthreads();
        if (t == 0) attn[b] = sred[0] + sred[1] + sred[2] + sred[3];
    }
    grid.sync();

    // ---------- P3: x[b] = relu(Wc[b,:] . [emb, attn] + bc[b]) ----------
    {
        int tk = tok[0];
        const float4* er = (const float4*)(emb_w + (size_t)tk * H);
        sh4[t]       = er[t];
        sh4[256 + t] = ((const float4*)attn)[t];
        __syncthreads();
        const float4* wr = (const float4*)(Wc + (size_t)b * H2);
        float acc = dot4(wr[t], sh4[t]) + dot4(wr[256 + t], sh4[256 + t]);
        acc = wave_red_sum(acc);
        if (lane == 0) sred[wv] = acc;
        __syncthreads();
        if (t == 0) xv[b] = fmaxf(sred[0] + sred[1] + sred[2] + sred[3] + bc[b], 0.f);
        __syncthreads();
    }
    grid.sync();

    // ---------- P4: gi rows r,z,n for unit b + GRU elementwise ----------
    {
        if (wv < 3) {
            const float4* wr = (const float4*)(w_ih + (size_t)(wv * H + b) * H);
            const float4* x4 = (const float4*)xv;
            float acc = 0.f;
            #pragma unroll
            for (int j = 0; j < 4; ++j) acc += dot4(wr[j*64 + lane], x4[j*64 + lane]);
            acc = wave_red_sum(acc);
            if (lane == 0) sred[wv] = acc;
        }
        __syncthreads();
        if (t == 0) {
            float gir = sred[0] + b_ih[b];
            float giz = sred[1] + b_ih[H + b];
            float gin = sred[2] + b_ih[2 * H + b];
            float r = 1.f / (1.f + expf(-(gir + gh[b])));
            float z = 1.f / (1.f + expf(-(giz + gh[H + b])));
            float n = tanhf(gin + r * gh[2 * H + b]);
            float h = (1.f - z) * n + z * h0[b];
            hnew[b] = h;
            d_out[V + b] = h;
        }
    }
    grid.sync();

    // ---------- P5: logits (grid-stride, 2 rows/wave) + per-block LSE partial ----------
    {
        sh4[t] = ((const float4*)hnew)[t];
        __syncthreads();
        float m_run = -INFINITY, s_run = 0.f;
        for (int g = b; g < NG; g += NB) {
            int r0 = g * 8 + wv * 2;
            if (r0 + 1 < V) {
                const float4* w0 = (const float4*)(out_w + (size_t)r0 * H);
                const float4* w1 = w0 + 256;
                float a0 = 0.f, a1 = 0.f;
                #pragma unroll
                for (int j = 0; j < 4; ++j) {
                    float4 hv = sh4[j*64 + lane];
                    a0 += dot4(w0[j*64 + lane], hv);
                    a1 += dot4(w1[j*64 + lane], hv);
                }
                #pragma unroll
                for (int off = 32; off > 0; off >>= 1) {
                    a0 += __shfl_down(a0, off, 64);
                    a1 += __shfl_down(a1, off, 64);
                }
                if (lane == 0) {
                    float v0 = a0 + out_b[r0];
                    float v1 = a1 + out_b[r0 + 1];
                    d_out[r0]     = v0;
                    d_out[r0 + 1] = v1;
                    float mn = fmaxf(m_run, fmaxf(v0, v1));
                    s_run = s_run * expf(m_run - mn) + expf(v0 - mn) + expf(v1 - mn);
                    m_run = mn;
                }
            } else if (r0 < V) {
                const float4* w0 = (const float4*)(out_w + (size_t)r0 * H);
                float a0 = 0.f;
                #pragma unroll
                for (int j = 0; j < 4; ++j) a0 += dot4(w0[j*64 + lane], sh4[j*64 + lane]);
                a0 = wave_red_sum(a0);
                if (lane == 0) {
                    float v0 = a0 + out_b[r0];
                    d_out[r0] = v0;
                    float mn = fmaxf(m_run, v0);
                    s_run = s_run * expf(m_run - mn) + expf(v0 - mn);
                    m_run = mn;
                }
            }
        }
        if (lane == 0) { sred[wv] = m_run; sred[4 + wv] = s_run; }
        __syncthreads();
        if (t == 0) {
            float M = fmaxf(fmaxf(sred[0], sred[1]), fmaxf(sred[2], sred[3]));
            float S = 0.f;
            #pragma unroll
            for (int k = 0; k < 4; ++k) S += sred[4 + k] * expf(sred[k] - M);
            pm[b] = M; ps[b] = S;
        }
    }
    grid.sync();

    // ---------- P6: combine 1024 partials (redundant/block, L2-hot) + subtract ----------
    {
        float m = -INFINITY, s = 0.f;
        #pragma unroll
        for (int k = 0; k < 4; ++k) {
            int i = t * 4 + k;
            float mi = pm[i], si = ps[i];
            float mn = fmaxf(m, mi);
            s = s * expf(m - mn) + si * expf(mi - mn);
            m = mn;
        }
        #pragma unroll
        for (int off = 32; off > 0; off >>= 1) {
            float mo = __shfl_down(m, off, 64);
            float so = __shfl_down(s, off, 64);
            float mn = fmaxf(m, mo);
            s = s * expf(m - mn) + so * expf(mo - mn);
            m = mn;
        }
        if (lane == 0) { sred[wv] = m; sred[4 + wv] = s; }
        __syncthreads();
        float M = fmaxf(fmaxf(sred[0], sred[1]), fmaxf(sred[2], sred[3]));
        float S = 0.f;
        #pragma unroll
        for (int k = 0; k < 4; ++k) S += sred[4 + k] * expf(sred[k] - M);
        float off = M + logf(S);
        int i = b * NT + t;
        if (i < V) d_out[i] -= off;
    }
}

extern "C" void kernel_launch(void* const* d_in, const int* in_sizes, int n_in,
                              void* d_out, int out_size, void* d_ws, size_t ws_size,
                              hipStream_t stream) {
    const int*   tok    = (const int*)d_in[0];
    const float* hidden = (const float*)d_in[1];
    const float* enc    = (const float*)d_in[2];
    const float* emb_w  = (const float*)d_in[3];
    const float* Wc     = (const float*)d_in[4];
    const float* bc     = (const float*)d_in[5];
    const float* w_ih   = (const float*)d_in[6];
    const float* w_hh   = (const float*)d_in[7];
    const float* b_ih   = (const float*)d_in[8];
    const float* b_hh   = (const float*)d_in[9];
    const float* out_w  = (const float*)d_in[10];
    const float* out_b  = (const float*)d_in[11];
    float* out = (float*)d_out;
    float* ws  = (float*)d_ws;

    void* args[] = { &tok, &hidden, &enc, &emb_w, &Wc, &bc,
                     &w_ih, &w_hh, &b_ih, &b_hh, &out_w, &out_b,
                     &out, &ws };
    hipLaunchCooperativeKernel((const void*)k_fused, dim3(NB), dim3(NT),
                               args, 0, stream);
}

// Round 2
// 423.821 us; speedup vs baseline: 2.2803x; 2.2803x over previous
//
#include <hip/hip_runtime.h>
#include <math.h>

#define H  1024
#define H2 2048
#define V  50257
#define L  512
#define NL 3142   // ceil(V/16) blocks for k_logits (16 rows/block)

__device__ __forceinline__ float dot4(float4 a, float4 b) {
    return a.x*b.x + a.y*b.y + a.z*b.z + a.w*b.w;
}
__device__ __forceinline__ float wave_red_sum(float v) {
    #pragma unroll
    for (int off = 32; off > 0; off >>= 1) v += __shfl_down(v, off, 64);
    return v;
}
__device__ __forceinline__ float wave_red_max(float v) {
    #pragma unroll
    for (int off = 32; off > 0; off >>= 1) v = fmaxf(v, __shfl_down(v, off, 64));
    return v;
}

// ---- K1: scores[l] = dot(h0, enc[l]), 512 blocks -------------------------
__global__ void __launch_bounds__(256) k_scores(
        const float* __restrict__ h0, const float* __restrict__ enc,
        float* __restrict__ scores) {
    __shared__ float sred[4];
    int t = threadIdx.x, lane = t & 63, wv = t >> 6;
    int l = blockIdx.x;
    float4 a = ((const float4*)(enc + (size_t)l * H))[t];
    float4 b = ((const float4*)h0)[t];
    float acc = wave_red_sum(dot4(a, b));
    if (lane == 0) sred[wv] = acc;
    __syncthreads();
    if (t == 0) scores[l] = sred[0] + sred[1] + sred[2] + sred[3];
}

// ---- K2: redundant softmax per block + 4 attn columns per block ----------
__global__ void __launch_bounds__(256) k_attn(
        const float* __restrict__ enc, const float* __restrict__ scores,
        float* __restrict__ attn, float* __restrict__ d_out) {
    __shared__ float wl[L];
    __shared__ float sred[4];
    int t = threadIdx.x, lane = t & 63, wv = t >> 6;
    float s0 = scores[t], s1 = scores[t + 256];
    float m = wave_red_max(fmaxf(s0, s1));
    if (lane == 0) sred[wv] = m;
    __syncthreads();
    float gmax = fmaxf(fmaxf(sred[0], sred[1]), fmaxf(sred[2], sred[3]));
    __syncthreads();
    float e0 = expf(s0 - gmax), e1 = expf(s1 - gmax);
    float ssum = wave_red_sum(e0 + e1);
    if (lane == 0) sred[wv] = ssum;
    __syncthreads();
    float inv = 1.f / (sred[0] + sred[1] + sred[2] + sred[3]);
    float w0 = e0 * inv, w1 = e1 * inv;
    wl[t] = w0; wl[t + 256] = w1;
    if (blockIdx.x == 0) {
        d_out[V + H + t]       = w0;
        d_out[V + H + 256 + t] = w1;
    }
    __syncthreads();
    // wave wv owns column col; lane sums 8 strided rows (independent loads)
    int col = blockIdx.x * 4 + wv;
    float acc = 0.f;
    #pragma unroll
    for (int k = 0; k < 8; ++k)
        acc += wl[k * 64 + lane] * enc[(size_t)(k * 64 + lane) * H + col];
    acc = wave_red_sum(acc);
    if (lane == 0) attn[col] = acc;
}

// ---- K3: x = relu([embedded, attn] @ Wc^T + bc) --------------------------
__global__ void __launch_bounds__(256) k_combine(
        const float* __restrict__ emb_w, const int* __restrict__ tok,
        const float* __restrict__ attn, const float* __restrict__ Wc,
        const float* __restrict__ bc, float* __restrict__ x) {
    __shared__ float comb[H2];
    int t = threadIdx.x;
    int tk = tok[0];
    ((float4*)comb)[t]       = ((const float4*)(emb_w + (size_t)tk * H))[t];
    ((float4*)comb)[t + 256] = ((const float4*)attn)[t];
    __syncthreads();
    int lane = t & 63, wv = t >> 6;
    int row = blockIdx.x * 4 + wv;
    const float4* wr = (const float4*)(Wc + (size_t)row * H2);
    float acc = 0.f;
    #pragma unroll
    for (int j = 0; j < 8; ++j)
        acc += dot4(wr[j * 64 + lane], ((const float4*)comb)[j * 64 + lane]);
    acc = wave_red_sum(acc);
    if (lane == 0) x[row] = fmaxf(acc + bc[row], 0.f);
}

// ---- K4: full GRU — gi (x @ w_ih) AND gh (h0 @ w_hh) + elementwise -------
// wave wv of block b owns unit i = b*4+wv: 6 dots of length 1024, 24 loads in flight
__global__ void __launch_bounds__(256, 4) k_gru(
        const float* __restrict__ x, const float* __restrict__ h0,
        const float* __restrict__ w_ih, const float* __restrict__ b_ih,
        const float* __restrict__ w_hh, const float* __restrict__ b_hh,
        float* __restrict__ d_out, float* __restrict__ hnew) {
    int t = threadIdx.x, lane = t & 63, wv = t >> 6;
    int i = blockIdx.x * 4 + wv;                    // 0..1023
    const float4* x4 = (const float4*)x;
    const float4* h4 = (const float4*)h0;
    float gi[3], gh[3];
    #pragma unroll
    for (int k = 0; k < 3; ++k) {
        const float4* wi = (const float4*)(w_ih + (size_t)(k * H + i) * H);
        const float4* wh = (const float4*)(w_hh + (size_t)(k * H + i) * H);
        float ai = 0.f, ah = 0.f;
        #pragma unroll
        for (int j = 0; j < 4; ++j) {
            ai += dot4(wi[j * 64 + lane], x4[j * 64 + lane]);
            ah += dot4(wh[j * 64 + lane], h4[j * 64 + lane]);
        }
        #pragma unroll
        for (int off = 32; off > 0; off >>= 1) {
            ai += __shfl_down(ai, off, 64);
            ah += __shfl_down(ah, off, 64);
        }
        gi[k] = ai; gh[k] = ah;
    }
    if (lane == 0) {
        float r = 1.f / (1.f + expf(-(gi[0] + b_ih[i]       + gh[0] + b_hh[i])));
        float z = 1.f / (1.f + expf(-(gi[1] + b_ih[H + i]   + gh[1] + b_hh[H + i])));
        float n = tanhf(gi[2] + b_ih[2 * H + i] + r * (gh[2] + b_hh[2 * H + i]));
        float h = (1.f - z) * n + z * h0[i];
        d_out[V + i] = h;
        hnew[i] = h;
    }
}

// ---- K5: logits, 4 rows/wave (16 loads in flight) + per-block LSE partial -
__global__ void __launch_bounds__(256, 4) k_logits(
        const float* __restrict__ hnew, const float* __restrict__ out_w,
        const float* __restrict__ out_b, float* __restrict__ d_out,
        float* __restrict__ pm, float* __restrict__ ps) {
    __shared__ float4 hs4[256];
    __shared__ float sm[4], ss[4];
    int t = threadIdx.x, lane = t & 63, wv = t >> 6;
    hs4[t] = ((const float4*)hnew)[t];
    __syncthreads();
    int base = blockIdx.x * 16 + wv * 4;
    const float4* wr[4];
    #pragma unroll
    for (int r = 0; r < 4; ++r) {
        int row = (base + r < V) ? base + r : V - 1;   // clamp: safe load
        wr[r] = (const float4*)(out_w + (size_t)row * H);
    }
    float a[4] = {0.f, 0.f, 0.f, 0.f};
    #pragma unroll
    for (int j = 0; j < 4; ++j) {
        float4 hv = hs4[j * 64 + lane];
        #pragma unroll
        for (int r = 0; r < 4; ++r) a[r] += dot4(wr[r][j * 64 + lane], hv);
    }
    #pragma unroll
    for (int off = 32; off > 0; off >>= 1) {
        #pragma unroll
        for (int r = 0; r < 4; ++r) a[r] += __shfl_down(a[r], off, 64);
    }
    if (lane == 0) {
        float v[4];
        float m = -INFINITY;
        #pragma unroll
        for (int r = 0; r < 4; ++r) {
            int row = base + r;
            if (row < V) {
                v[r] = a[r] + out_b[row];
                d_out[row] = v[r];
                m = fmaxf(m, v[r]);
            } else v[r] = -INFINITY;
        }
        float s = 0.f;
        #pragma unroll
        for (int r = 0; r < 4; ++r)
            if (base + r < V) s += expf(v[r] - m);
        sm[wv] = m; ss[wv] = s;
    }
    __syncthreads();
    if (t == 0) {
        float M = fmaxf(fmaxf(sm[0], sm[1]), fmaxf(sm[2], sm[3]));
        float S = 0.f;
        #pragma unroll
        for (int k = 0; k < 4; ++k)
            if (sm[k] > -INFINITY) S += ss[k] * expf(sm[k] - M);
        pm[blockIdx.x] = M; ps[blockIdx.x] = S;
    }
}

// ---- K6: redundant combine of NL partials per block + subtract -----------
__global__ void __launch_bounds__(256) k_logp(
        float* __restrict__ d_out, const float* __restrict__ pm,
        const float* __restrict__ ps) {
    __shared__ float sm[4], ss[4];
    int t = threadIdx.x, lane = t & 63, wv = t >> 6;
    float m = -INFINITY, s = 0.f;
    for (int i = t; i < NL; i += 256) {
        float mi = pm[i], si = ps[i];
        float mn = fmaxf(m, mi);
        s = s * expf(m - mn) + si * expf(mi - mn);
        m = mn;
    }
    #pragma unroll
    for (int off = 32; off > 0; off >>= 1) {
        float mo = __shfl_down(m, off, 64);
        float so = __shfl_down(s, off, 64);
        float mn = fmaxf(m, mo);
        s = s * expf(m - mn) + so * expf(mo - mn);
        m = mn;
    }
    if (lane == 0) { sm[wv] = m; ss[wv] = s; }
    __syncthreads();
    float M = fmaxf(fmaxf(sm[0], sm[1]), fmaxf(sm[2], sm[3]));
    float S = 0.f;
    #pragma unroll
    for (int k = 0; k < 4; ++k) S += ss[k] * expf(sm[k] - M);
    float off = M + logf(S);
    int i = blockIdx.x * 256 + t;
    if (i < V) d_out[i] -= off;
}

extern "C" void kernel_launch(void* const* d_in, const int* in_sizes, int n_in,
                              void* d_out, int out_size, void* d_ws, size_t ws_size,
                              hipStream_t stream) {
    const int*   tok    = (const int*)d_in[0];
    const float* hidden = (const float*)d_in[1];
    const float* enc    = (const float*)d_in[2];
    const float* emb_w  = (const float*)d_in[3];
    const float* Wc     = (const float*)d_in[4];
    const float* bc     = (const float*)d_in[5];
    const float* w_ih   = (const float*)d_in[6];
    const float* w_hh   = (const float*)d_in[7];
    const float* b_ih   = (const float*)d_in[8];
    const float* b_hh   = (const float*)d_in[9];
    const float* out_w  = (const float*)d_in[10];
    const float* out_b  = (const float*)d_in[11];
    float* out = (float*)d_out;
    float* ws  = (float*)d_ws;

    float* scores = ws;             // 512
    float* attn   = ws + 4096;      // 1024
    float* xbuf   = ws + 5120;      // 1024
    float* hnew   = ws + 6144;      // 1024
    float* pm     = ws + 8192;      // NL
    float* psum   = ws + 12288;     // NL

    k_scores <<<512, 256, 0, stream>>>(hidden, enc, scores);
    k_attn   <<<256, 256, 0, stream>>>(enc, scores, attn, out);
    k_combine<<<256, 256, 0, stream>>>(emb_w, tok, attn, Wc, bc, xbuf);
    k_gru    <<<256, 256, 0, stream>>>(xbuf, hidden, w_ih, b_ih, w_hh, b_hh, out, hnew);
    k_logits <<<NL,  256, 0, stream>>>(hnew, out_w, out_b, out, pm, psum);
    k_logp   <<<(V + 255) / 256, 256, 0, stream>>>(out, pm, psum);
}

// Round 3
// 420.711 us; speedup vs baseline: 2.2971x; 1.0074x over previous
//
#include <hip/hip_runtime.h>
#include <math.h>

#define H   1024
#define H2  2048
#define V   50257
#define L   512
#define NL  3142   // ceil(V/16) blocks for k_logits (16 rows/block)
#define NAB 16     // attn partial blocks (32 rows each)

__device__ __forceinline__ float dot4(float4 a, float4 b) {
    return a.x*b.x + a.y*b.y + a.z*b.z + a.w*b.w;
}
__device__ __forceinline__ float wave_red_sum(float v) {
    #pragma unroll
    for (int off = 32; off > 0; off >>= 1) v += __shfl_down(v, off, 64);
    return v;
}
__device__ __forceinline__ float wave_red_max(float v) {
    #pragma unroll
    for (int off = 32; off > 0; off >>= 1) v = fmaxf(v, __shfl_down(v, off, 64));
    return v;
}

// ---- K1: scores[l] = dot(h0, enc[l]), 512 blocks --------------------------
__global__ void __launch_bounds__(256) k_scores(
        const float* __restrict__ h0, const float* __restrict__ enc,
        float* __restrict__ scores) {
    __shared__ float sred[4];
    int t = threadIdx.x, lane = t & 63, wv = t >> 6;
    int l = blockIdx.x;
    float4 a = ((const float4*)(enc + (size_t)l * H))[t];
    float4 b = ((const float4*)h0)[t];
    float acc = wave_red_sum(dot4(a, b));
    if (lane == 0) sred[wv] = acc;
    __syncthreads();
    if (t == 0) scores[l] = sred[0] + sred[1] + sred[2] + sred[3];
}

// ---- K2: redundant softmax per block; block b sums rows [32b,32b+32) ------
// COALESCED: thread t reads float4 column-slice of each row (256 thr = full row)
__global__ void __launch_bounds__(256) k_attn_part(
        const float* __restrict__ enc, const float* __restrict__ scores,
        float* __restrict__ partial, float* __restrict__ d_out) {
    __shared__ float wl[L];
    __shared__ float sred[4];
    int t = threadIdx.x, lane = t & 63, wv = t >> 6;
    float s0 = scores[t], s1 = scores[t + 256];
    float m = wave_red_max(fmaxf(s0, s1));
    if (lane == 0) sred[wv] = m;
    __syncthreads();
    float gmax = fmaxf(fmaxf(sred[0], sred[1]), fmaxf(sred[2], sred[3]));
    __syncthreads();
    float e0 = expf(s0 - gmax), e1 = expf(s1 - gmax);
    float ssum = wave_red_sum(e0 + e1);
    if (lane == 0) sred[wv] = ssum;
    __syncthreads();
    float inv = 1.f / (sred[0] + sred[1] + sred[2] + sred[3]);
    float w0 = e0 * inv, w1 = e1 * inv;
    wl[t] = w0; wl[t + 256] = w1;
    if (blockIdx.x == 0) {                       // attn_weights output
        d_out[V + H + t]       = w0;
        d_out[V + H + 256 + t] = w1;
    }
    __syncthreads();
    int r0 = blockIdx.x * 32;
    float4 acc = make_float4(0.f, 0.f, 0.f, 0.f);
    #pragma unroll 8
    for (int k = 0; k < 32; ++k) {
        float w  = wl[r0 + k];
        float4 e = ((const float4*)(enc + (size_t)(r0 + k) * H))[t];
        acc.x += w * e.x; acc.y += w * e.y; acc.z += w * e.z; acc.w += w * e.w;
    }
    ((float4*)(partial + (size_t)blockIdx.x * H))[t] = acc;
}

// ---- K3: sum 16 attn partials + x = relu([emb, attn] @ Wc^T + bc) ---------
__global__ void __launch_bounds__(256) k_combine(
        const float* __restrict__ emb_w, const int* __restrict__ tok,
        const float* __restrict__ partial, const float* __restrict__ Wc,
        const float* __restrict__ bc, float* __restrict__ x) {
    __shared__ float comb[H2];
    int t = threadIdx.x;
    float4 a = make_float4(0.f, 0.f, 0.f, 0.f);
    #pragma unroll
    for (int b = 0; b < NAB; ++b) {
        float4 p = ((const float4*)(partial + (size_t)b * H))[t];
        a.x += p.x; a.y += p.y; a.z += p.z; a.w += p.w;
    }
    int tk = tok[0];
    ((float4*)comb)[t]       = ((const float4*)(emb_w + (size_t)tk * H))[t];
    ((float4*)comb)[t + 256] = a;
    __syncthreads();
    int lane = t & 63, wv = t >> 6;
    int row = blockIdx.x * 4 + wv;
    const float4* wr = (const float4*)(Wc + (size_t)row * H2);
    float acc = 0.f;
    #pragma unroll
    for (int j = 0; j < 8; ++j)
        acc += dot4(wr[j * 64 + lane], ((const float4*)comb)[j * 64 + lane]);
    acc = wave_red_sum(acc);
    if (lane == 0) x[row] = fmaxf(acc + bc[row], 0.f);
}

// ---- K4: full GRU; 6 accumulators, all 32 loads independent ---------------
__global__ void __launch_bounds__(256) k_gru(
        const float* __restrict__ x, const float* __restrict__ h0,
        const float* __restrict__ w_ih, const float* __restrict__ b_ih,
        const float* __restrict__ w_hh, const float* __restrict__ b_hh,
        float* __restrict__ d_out, float* __restrict__ hnew) {
    int t = threadIdx.x, lane = t & 63, wv = t >> 6;
    int i = blockIdx.x * 4 + wv;                    // 0..1023
    const float4* x4 = (const float4*)x;
    const float4* h4 = (const float4*)h0;
    const float4* wi0 = (const float4*)(w_ih + (size_t)i * H);
    const float4* wi1 = (const float4*)(w_ih + (size_t)(H + i) * H);
    const float4* wi2 = (const float4*)(w_ih + (size_t)(2 * H + i) * H);
    const float4* wh0 = (const float4*)(w_hh + (size_t)i * H);
    const float4* wh1 = (const float4*)(w_hh + (size_t)(H + i) * H);
    const float4* wh2 = (const float4*)(w_hh + (size_t)(2 * H + i) * H);
    float ai0 = 0.f, ai1 = 0.f, ai2 = 0.f, ah0 = 0.f, ah1 = 0.f, ah2 = 0.f;
    #pragma unroll
    for (int j = 0; j < 4; ++j) {
        int idx = j * 64 + lane;
        float4 xv = x4[idx], hv = h4[idx];
        ai0 += dot4(wi0[idx], xv);
        ai1 += dot4(wi1[idx], xv);
        ai2 += dot4(wi2[idx], xv);
        ah0 += dot4(wh0[idx], hv);
        ah1 += dot4(wh1[idx], hv);
        ah2 += dot4(wh2[idx], hv);
    }
    #pragma unroll
    for (int off = 32; off > 0; off >>= 1) {
        ai0 += __shfl_down(ai0, off, 64);
        ai1 += __shfl_down(ai1, off, 64);
        ai2 += __shfl_down(ai2, off, 64);
        ah0 += __shfl_down(ah0, off, 64);
        ah1 += __shfl_down(ah1, off, 64);
        ah2 += __shfl_down(ah2, off, 64);
    }
    if (lane == 0) {
        float r = 1.f / (1.f + expf(-(ai0 + b_ih[i]         + ah0 + b_hh[i])));
        float z = 1.f / (1.f + expf(-(ai1 + b_ih[H + i]     + ah1 + b_hh[H + i])));
        float n = tanhf(ai2 + b_ih[2 * H + i] + r * (ah2 + b_hh[2 * H + i]));
        float h = (1.f - z) * n + z * h0[i];
        d_out[V + i] = h;
        hnew[i] = h;
    }
}

// ---- K5: logits, 4 rows/wave, no staging barrier + per-block LSE partial --
__global__ void __launch_bounds__(256, 4) k_logits(
        const float* __restrict__ hnew, const float* __restrict__ out_w,
        const float* __restrict__ out_b, float* __restrict__ d_out,
        float* __restrict__ pm, float* __restrict__ ps) {
    __shared__ float sm[4], ss[4];
    int t = threadIdx.x, lane = t & 63, wv = t >> 6;
    int base = blockIdx.x * 16 + wv * 4;
    const float4* h4 = (const float4*)hnew;
    const float4* wr[4];
    #pragma unroll
    for (int r = 0; r < 4; ++r) {
        int row = (base + r < V) ? base + r : V - 1;   // clamp: safe load
        wr[r] = (const float4*)(out_w + (size_t)row * H);
    }
    float a[4] = {0.f, 0.f, 0.f, 0.f};
    #pragma unroll
    for (int j = 0; j < 4; ++j) {
        float4 hv = h4[j * 64 + lane];                 // L2-hot broadcast
        #pragma unroll
        for (int r = 0; r < 4; ++r) a[r] += dot4(wr[r][j * 64 + lane], hv);
    }
    #pragma unroll
    for (int off = 32; off > 0; off >>= 1) {
        #pragma unroll
        for (int r = 0; r < 4; ++r) a[r] += __shfl_down(a[r], off, 64);
    }
    if (lane == 0) {
        float v[4];
        float m = -INFINITY;
        #pragma unroll
        for (int r = 0; r < 4; ++r) {
            int row = base + r;
            if (row < V) {
                v[r] = a[r] + out_b[row];
                d_out[row] = v[r];
                m = fmaxf(m, v[r]);
            } else v[r] = -INFINITY;
        }
        float s = 0.f;
        #pragma unroll
        for (int r = 0; r < 4; ++r)
            if (base + r < V) s += expf(v[r] - m);
        sm[wv] = m; ss[wv] = s;
    }
    __syncthreads();
    if (t == 0) {
        float M = fmaxf(fmaxf(sm[0], sm[1]), fmaxf(sm[2], sm[3]));
        float S = 0.f;
        #pragma unroll
        for (int k = 0; k < 4; ++k)
            if (sm[k] > -INFINITY) S += ss[k] * expf(sm[k] - M);
        pm[blockIdx.x] = M; ps[blockIdx.x] = S;
    }
}

// ---- K6: redundant combine of NL partials per block + subtract ------------
__global__ void __launch_bounds__(256) k_logp(
        float* __restrict__ d_out, const float* __restrict__ pm,
        const float* __restrict__ ps) {
    __shared__ float sm[4], ss[4];
    int t = threadIdx.x, lane = t & 63, wv = t >> 6;
    float m = -INFINITY, s = 0.f;
    for (int i = t; i < NL; i += 256) {
        float mi = pm[i], si = ps[i];
        float mn = fmaxf(m, mi);
        s = s * expf(m - mn) + si * expf(mi - mn);
        m = mn;
    }
    #pragma unroll
    for (int off = 32; off > 0; off >>= 1) {
        float mo = __shfl_down(m, off, 64);
        float so = __shfl_down(s, off, 64);
        float mn = fmaxf(m, mo);
        s = s * expf(m - mn) + so * expf(mo - mn);
        m = mn;
    }
    if (lane == 0) { sm[wv] = m; ss[wv] = s; }
    __syncthreads();
    float M = fmaxf(fmaxf(sm[0], sm[1]), fmaxf(sm[2], sm[3]));
    float S = 0.f;
    #pragma unroll
    for (int k = 0; k < 4; ++k) S += ss[k] * expf(sm[k] - M);
    float off = M + logf(S);
    int i = blockIdx.x * 256 + t;
    if (i < V) d_out[i] -= off;
}

extern "C" void kernel_launch(void* const* d_in, const int* in_sizes, int n_in,
                              void* d_out, int out_size, void* d_ws, size_t ws_size,
                              hipStream_t stream) {
    const int*   tok    = (const int*)d_in[0];
    const float* hidden = (const float*)d_in[1];
    const float* enc    = (const float*)d_in[2];
    const float* emb_w  = (const float*)d_in[3];
    const float* Wc     = (const float*)d_in[4];
    const float* bc     = (const float*)d_in[5];
    const float* w_ih   = (const float*)d_in[6];
    const float* w_hh   = (const float*)d_in[7];
    const float* b_ih   = (const float*)d_in[8];
    const float* b_hh   = (const float*)d_in[9];
    const float* out_w  = (const float*)d_in[10];
    const float* out_b  = (const float*)d_in[11];
    float* out = (float*)d_out;
    float* ws  = (float*)d_ws;

    float* scores  = ws;             // 512
    float* partial = ws + 1024;      // 16*1024
    float* xbuf    = ws + 17408;     // 1024
    float* hnew    = ws + 18432;     // 1024
    float* pm      = ws + 19456;     // NL (pad 3584)
    float* psum    = ws + 23040;     // NL

    k_scores   <<<512, 256, 0, stream>>>(hidden, enc, scores);
    k_attn_part<<<NAB, 256, 0, stream>>>(enc, scores, partial, out);
    k_combine  <<<256, 256, 0, stream>>>(emb_w, tok, partial, Wc, bc, xbuf);
    k_gru      <<<256, 256, 0, stream>>>(xbuf, hidden, w_ih, b_ih, w_hh, b_hh, out, hnew);
    k_logits   <<<NL,  256, 0, stream>>>(hnew, out_w, out_b, out, pm, psum);
    k_logp     <<<(V + 255) / 256, 256, 0, stream>>>(out, pm, psum);
}